// Round 1
// baseline (11808.191 us; speedup 1.0000x reference)
//
#include <hip/hip_runtime.h>
#include <math.h>

// ---------------- problem constants ----------------
#define N_USER   50000
#define N_MOVIE  20000
#define N_REVIEW 200000
#define NTOT     270000
#define NE       200000
#define HIDC     256
#define INC      768
#define OUTC     128

__device__ __forceinline__ float lrelu_f(float x){ return x > 0.f ? x : 0.01f*x; }

// order-preserving float<->uint encoding for atomicMax on floats (handles negatives)
__device__ __forceinline__ unsigned fenc(float f){
  unsigned u = __float_as_uint(f);
  return (u & 0x80000000u) ? ~u : (u | 0x80000000u);
}
__device__ __forceinline__ float fdec(unsigned e){
  return (e & 0x80000000u) ? __uint_as_float(e & 0x7FFFFFFFu) : __uint_as_float(~e);
}

// ---------------- effective-weight prep ----------------
// Wk_eff[l,s] = Wk[l,s] @ blockdiag_h(a_rel[l,e(s)]) * (p_rel[l,e(s),h] / sqrt(D))
// Wv_eff[l,s] = Wv[l,s] @ blockdiag_h(m_rel[l,e(s)])   (same for biases)
// source type s -> edge index: s=0->e1, s=1->e0, s=2->e2
__global__ void prep_weights(const float* __restrict__ Wk, const float* __restrict__ bk,
                             const float* __restrict__ Wv, const float* __restrict__ bv,
                             const float* __restrict__ a_rel, const float* __restrict__ m_rel,
                             const float* __restrict__ p_rel,
                             float* __restrict__ WkE, float* __restrict__ bkE,
                             float* __restrict__ WvE, float* __restrict__ bvE)
{
  int bid = blockIdx.x;
  int kv  = bid / (2*3*257);          // 0 = key path, 1 = value path
  int rem = bid % (2*3*257);
  int ls  = rem / 257;
  int i   = rem % 257;                // 256 == bias row
  int l = ls / 3, s = ls % 3;
  const int es_map[3] = {1, 0, 2};
  int e = es_map[s];
  int j = threadIdx.x;                // output column 0..255
  int h = j >> 5, eo = j & 31;

  const float* rel = (kv == 0 ? a_rel : m_rel) + (size_t)((l*3+e)*8 + h)*1024 + eo; // [d*32]
  float scale = 1.f;
  if (kv == 0) scale = p_rel[(l*3+e)*8 + h] * 0.17677669529663687f; // 1/sqrt(32)

  float acc = 0.f;
  if (i < 256) {
    const float* wrow = (kv == 0 ? Wk : Wv) + ((size_t)(l*3+s)*256 + i)*256 + h*32;
    #pragma unroll
    for (int d = 0; d < 32; ++d) acc += wrow[d] * rel[d*32];
    acc *= scale;
    (kv == 0 ? WkE : WvE)[((size_t)(l*3+s)*256 + i)*256 + j] = acc;
  } else {
    const float* brow = (kv == 0 ? bk : bv) + (size_t)(l*3+s)*256 + h*32;
    #pragma unroll
    for (int d = 0; d < 32; ++d) acc += brow[d] * rel[d*32];
    acc *= scale;
    (kv == 0 ? bkE : bvE)[(size_t)(l*3+s)*256 + j] = acc;
  }
}

// ---------------- fp32 tiled GEMM, C = epilogue(A@B + bias) ----------------
// A [M,K] rm, B [K,N] rm, C [M,N] rm.  mode 0: leaky_relu; 1: none;
// 2: g*(acc+bias) + (1-g)*skipbuf  with g = sigmoid(*skipscalar)
__global__ __launch_bounds__(256) void gemm_f32(
    const float* __restrict__ A, const float* __restrict__ B,
    const float* __restrict__ bias, float* C,
    int M, int N, int K, int mode,
    const float* skipbuf, const float* __restrict__ skipscalar)
{
  __shared__ float As[16][64];
  __shared__ float Bs[16][64];
  const int tid = threadIdx.x;
  const int bm = blockIdx.y * 64, bn = blockIdx.x * 64;
  const int tm = (tid >> 4) << 2, tn = (tid & 15) << 2;
  const int am = tid >> 2,  akq = (tid & 3) << 2;   // A tile: 64 rows x 16 k, float4/thread
  const int bkr = tid >> 4, bnq = (tid & 15) << 2;  // B tile: 16 rows x 64 n, float4/thread
  float acc[4][4] = {};

  for (int k0 = 0; k0 < K; k0 += 16) {
    float4 av = make_float4(0.f, 0.f, 0.f, 0.f);
    int arow = bm + am;
    if (arow < M) av = *(const float4*)(A + (size_t)arow * K + k0 + akq);
    As[akq+0][am] = av.x; As[akq+1][am] = av.y; As[akq+2][am] = av.z; As[akq+3][am] = av.w;
    *(float4*)&Bs[bkr][bnq] = *(const float4*)(B + (size_t)(k0 + bkr) * N + bn + bnq);
    __syncthreads();
    #pragma unroll
    for (int k = 0; k < 16; ++k) {
      float a0 = As[k][tm+0], a1 = As[k][tm+1], a2 = As[k][tm+2], a3 = As[k][tm+3];
      float b0 = Bs[k][tn+0], b1 = Bs[k][tn+1], b2 = Bs[k][tn+2], b3 = Bs[k][tn+3];
      acc[0][0] += a0*b0; acc[0][1] += a0*b1; acc[0][2] += a0*b2; acc[0][3] += a0*b3;
      acc[1][0] += a1*b0; acc[1][1] += a1*b1; acc[1][2] += a1*b2; acc[1][3] += a1*b3;
      acc[2][0] += a2*b0; acc[2][1] += a2*b1; acc[2][2] += a2*b2; acc[2][3] += a2*b3;
      acc[3][0] += a3*b0; acc[3][1] += a3*b1; acc[3][2] += a3*b2; acc[3][3] += a3*b3;
    }
    __syncthreads();
  }

  float g = 0.f;
  if (mode == 2) g = 1.f / (1.f + expf(-skipscalar[0]));
  #pragma unroll
  for (int i = 0; i < 4; ++i) {
    int row = bm + tm + i;
    if (row < M) {
      #pragma unroll
      for (int j = 0; j < 4; ++j) {
        int col = bn + tn + j;
        float v = acc[i][j] + bias[col];
        if (mode == 0) v = lrelu_f(v);
        else if (mode == 2) v = g * v + (1.f - g) * skipbuf[(size_t)row * N + col];
        C[(size_t)row * N + col] = v;
      }
    }
  }
}

// ---------------- edge attention kernels ----------------
__global__ void init_attn(unsigned* __restrict__ maxb, float* __restrict__ denb, int n)
{
  int i = blockIdx.x * blockDim.x + threadIdx.x;
  if (i < n) { maxb[i] = fenc(-INFINITY); denb[i] = 0.f; }
}

__global__ void edge_logits(const float* __restrict__ Kb, const float* __restrict__ Qb,
                            const int* __restrict__ src, const int* __restrict__ dst,
                            float* __restrict__ lg, unsigned* __restrict__ maxb, int E)
{
  int idx = blockIdx.x * blockDim.x + threadIdx.x;
  if (idx >= E * 8) return;
  int e = idx >> 3, h = idx & 7;
  int r = src[e], c = dst[e];
  const float4* kp = (const float4*)(Kb + (size_t)r * 256 + h * 32);
  const float4* qp = (const float4*)(Qb + (size_t)c * 256 + h * 32);
  float s = 0.f;
  #pragma unroll
  for (int q = 0; q < 8; ++q) {
    float4 a = kp[q], b = qp[q];
    s += a.x*b.x + a.y*b.y + a.z*b.z + a.w*b.w;
  }
  lg[idx] = s;
  atomicMax(maxb + (size_t)c * 8 + h, fenc(s));
}

__global__ void edge_exp(const int* __restrict__ dst, float* __restrict__ lg,
                         const unsigned* __restrict__ maxb, float* __restrict__ denb, int E)
{
  int idx = blockIdx.x * blockDim.x + threadIdx.x;
  if (idx >= E * 8) return;
  int e = idx >> 3, h = idx & 7;
  int c = dst[e];
  float m = fdec(maxb[(size_t)c * 8 + h]);
  float ex = expf(lg[idx] - m);
  lg[idx] = ex;
  atomicAdd(denb + (size_t)c * 8 + h, ex);
}

__global__ void edge_scatter(const float* __restrict__ Vb, const int* __restrict__ src,
                             const int* __restrict__ dst, const float* __restrict__ lg,
                             const float* __restrict__ denb, float* outs, int E)
{
  int idx = blockIdx.x * blockDim.x + threadIdx.x;
  if (idx >= E * 64) return;
  int e = idx >> 6, r5 = idx & 63;
  int h = r5 >> 3, dq = r5 & 7;
  int r = src[e], c = dst[e];
  float w = lg[(size_t)e * 8 + h] / (denb[(size_t)c * 8 + h] + 1e-16f);
  float4 v = *(const float4*)(Vb + (size_t)r * 256 + h * 32 + dq * 4);
  float* o = outs + (size_t)c * 256 + h * 32 + dq * 4;
  atomicAdd(o + 0, v.x * w);
  atomicAdd(o + 1, v.y * w);
  atomicAdd(o + 2, v.z * w);
  atomicAdd(o + 3, v.w * w);
}

__global__ void gelu_inplace4(float4* x, size_t n4)
{
  size_t i = (size_t)blockIdx.x * blockDim.x + threadIdx.x;
  if (i >= n4) return;
  float4 v = x[i];
  v.x = 0.5f * v.x * (1.f + erff(v.x * 0.70710678118654752f));
  v.y = 0.5f * v.y * (1.f + erff(v.y * 0.70710678118654752f));
  v.z = 0.5f * v.z * (1.f + erff(v.z * 0.70710678118654752f));
  v.w = 0.5f * v.w * (1.f + erff(v.w * 0.70710678118654752f));
  x[i] = v;
}

// ---------------- launch ----------------
extern "C" void kernel_launch(void* const* d_in, const int* in_sizes, int n_in,
                              void* d_out, int out_size, void* d_ws, size_t ws_size,
                              hipStream_t stream)
{
  const float* xin[3] = { (const float*)d_in[0], (const float*)d_in[1], (const float*)d_in[2] };
  const int* src_e[3] = { (const int*)d_in[3], (const int*)d_in[5], (const int*)d_in[7] };
  const int* dst_e[3] = { (const int*)d_in[4], (const int*)d_in[6], (const int*)d_in[8] };
  const float* W1 = (const float*)d_in[9];   const float* b1 = (const float*)d_in[10];
  const float* W2 = (const float*)d_in[11];  const float* b2 = (const float*)d_in[12];
  const float* Wk = (const float*)d_in[13];  const float* bk = (const float*)d_in[14];
  const float* Wq = (const float*)d_in[15];  const float* bq = (const float*)d_in[16];
  const float* Wv = (const float*)d_in[17];  const float* bv = (const float*)d_in[18];
  const float* Wa = (const float*)d_in[19];  const float* ba = (const float*)d_in[20];
  const float* skip = (const float*)d_in[21];
  const float* a_rel = (const float*)d_in[22];
  const float* m_rel = (const float*)d_in[23];
  const float* p_rel = (const float*)d_in[24];
  float* out = (float*)d_out;

  const int Ns[3]  = { N_USER, N_MOVIE, N_REVIEW };
  const int off[3] = { 0, N_USER, N_USER + N_MOVIE };
  // edge types: (src_type, dst_type)
  const int es[3] = { 1, 0, 2 };
  const int et[3] = { 2, 2, 0 };

  float* ws = (float*)d_ws;
  const size_t NF = (size_t)NTOT * HIDC;     // 69.12M floats
  float* X    = ws;            ws += NF;
  float* Kb   = ws;            ws += NF;
  float* Qb   = ws;            ws += NF;
  float* Vb   = ws;            ws += NF;
  float* Outs = ws;            ws += NF;
  float* WkE  = ws;            ws += (size_t)2*3*256*256;
  float* WvE  = ws;            ws += (size_t)2*3*256*256;
  float* bkE  = ws;            ws += (size_t)2*3*256;
  float* bvE  = ws;            ws += (size_t)2*3*256;
  float* LG   = ws;            ws += (size_t)NE*8;
  unsigned* MAXB = (unsigned*)ws; ws += (size_t)N_REVIEW*8;
  float* DENB = ws;            ws += (size_t)N_REVIEW*8;

  // 1) effective K/V weights (fold a_rel/m_rel/p_rel into projections)
  prep_weights<<<2*3*257*2, 256, 0, stream>>>(Wk, bk, Wv, bv, a_rel, m_rel, p_rel,
                                              WkE, bkE, WvE, bvE);

  // 2) input MLP: X = lrelu(x @ W1 + b1)
  for (int t = 0; t < 3; ++t) {
    dim3 grid(HIDC/64, (Ns[t]+63)/64);
    gemm_f32<<<grid, 256, 0, stream>>>(xin[t], W1, b1, X + (size_t)off[t]*HIDC,
                                       Ns[t], HIDC, INC, 0, nullptr, nullptr);
  }

  // 3) HGT layers
  for (int l = 0; l < 2; ++l) {
    for (int t = 0; t < 3; ++t) {
      dim3 grid(HIDC/64, (Ns[t]+63)/64);
      size_t wo = (size_t)(l*3+t)*256*256, bo = (size_t)(l*3+t)*256, xo = (size_t)off[t]*HIDC;
      gemm_f32<<<grid, 256, 0, stream>>>(X + xo, WkE + wo, bkE + bo, Kb + xo,
                                         Ns[t], HIDC, HIDC, 1, nullptr, nullptr);
      gemm_f32<<<grid, 256, 0, stream>>>(X + xo, Wq + wo, bq + bo, Qb + xo,
                                         Ns[t], HIDC, HIDC, 1, nullptr, nullptr);
      gemm_f32<<<grid, 256, 0, stream>>>(X + xo, WvE + wo, bvE + bo, Vb + xo,
                                         Ns[t], HIDC, HIDC, 1, nullptr, nullptr);
    }
    hipMemsetAsync(Outs, 0, NF * sizeof(float), stream);
    for (int e = 0; e < 3; ++e) {
      int s = es[e], t = et[e];
      int nt8 = Ns[t] * 8;
      init_attn<<<(nt8+255)/256, 256, 0, stream>>>(MAXB, DENB, nt8);
      edge_logits<<<(NE*8+255)/256, 256, 0, stream>>>(Kb + (size_t)off[s]*HIDC,
                                                      Qb + (size_t)off[t]*HIDC,
                                                      src_e[e], dst_e[e], LG, MAXB, NE);
      edge_exp<<<(NE*8+255)/256, 256, 0, stream>>>(dst_e[e], LG, MAXB, DENB, NE);
      edge_scatter<<<(NE*64+255)/256, 256, 0, stream>>>(Vb + (size_t)off[s]*HIDC,
                                                        src_e[e], dst_e[e], LG, DENB,
                                                        Outs + (size_t)off[t]*HIDC, NE);
    }
    gelu_inplace4<<<(unsigned)((NF/4 + 255)/256), 256, 0, stream>>>((float4*)Outs, NF/4);
    for (int t = 0; t < 3; ++t) {
      dim3 grid(HIDC/64, (Ns[t]+63)/64);
      size_t wo = (size_t)(l*3+t)*256*256, bo = (size_t)(l*3+t)*256, xo = (size_t)off[t]*HIDC;
      gemm_f32<<<grid, 256, 0, stream>>>(Outs + xo, Wa + wo, ba + bo, X + xo,
                                         Ns[t], HIDC, HIDC, 2, X + xo, skip + l*3 + t);
    }
  }

  // 4) output MLP: out = lrelu(X @ W2 + b2), concat [user, movie, review]
  for (int t = 0; t < 3; ++t) {
    dim3 grid(OUTC/64, (Ns[t]+63)/64);
    gemm_f32<<<grid, 256, 0, stream>>>(X + (size_t)off[t]*HIDC, W2, b2,
                                       out + (size_t)off[t]*OUTC,
                                       Ns[t], OUTC, HIDC, 0, nullptr, nullptr);
  }
}